// Round 5
// baseline (191.958 us; speedup 1.0000x reference)
//
#include <hip/hip_runtime.h>

// LSGA fused kernel, round 5: occupancy-first.
//  - k_main: 8 n / 256 threads / ~29 KB LDS / __launch_bounds__(256,5)
//    -> 5 blocks/CU resident (was 1 at 120 KB). Xnb no longer staged in LDS:
//    scores reads A-frags from global (L2-hot), xbar re-gathers uint2's.
//  - k_pt: merged weight-prep + x-transpose (one launch).
//
// Algebra (exact given sum(attn)=1):
//   qk   = A·x_n + bA,            A = Wk^T Wq, bA = Wk^T bq          [128]
//   s[k] = (qk·x_nb[k] + h[k]·g + qk·b2 + x_n·u + bq·bk)/sqrt(C)
//          g = W2·qk [32], u = Wq^T bk, h[k] = relu(E[k]·W1 + b1)
//   attn = softmax_k(s)
//   w    = sum_k attn[k]*x_nb[k] + W2^T·(sum_k attn[k]*h[k]) + b2    [128]
//   out  = Wov·w + bov,           Wov = Wo·Wv, bov = Wo·bv + bo
//
// MFMA 16x16x32 lane mappings (verified in passing rounds 3/4):
//   A-frag:  A[m = lane&15][k = (lane>>4)*8 + j]
//   B-frag:  B[k = (lane>>4)*8 + j][n = lane&15]
//   C/D:     col = lane&15, row = (lane>>4)*4 + reg

using u16 = unsigned short;
using u32 = unsigned int;
using u64 = unsigned long long;

typedef short bf16x8 __attribute__((ext_vector_type(8)));
typedef float f32x4  __attribute__((ext_vector_type(4)));

__device__ __forceinline__ float bl(u32 u) { return __uint_as_float(u << 16); }
__device__ __forceinline__ float bh(u32 u) { return __uint_as_float(u & 0xffff0000u); }
__device__ __forceinline__ float b2f(u16 u) { return __uint_as_float(((u32)u) << 16); }
__device__ __forceinline__ u16 f2b(float f) {
    u32 u = __float_as_uint(f);
    u32 r = u + 0x7fffu + ((u >> 16) & 1u);   // RNE
    return (u16)(r >> 16);
}
__device__ __forceinline__ float dot8(uint4 wv, const float* xp) {
    float4 a = *(const float4*)xp;
    float4 b = *(const float4*)(xp + 4);
    return bl(wv.x)*a.x + bh(wv.x)*a.y + bl(wv.y)*a.z + bh(wv.y)*a.w
         + bl(wv.z)*b.x + bh(wv.z)*b.y + bl(wv.w)*b.z + bh(wv.w)*b.w;
}
__device__ __forceinline__ u64 pack4(float a, float b, float c, float d) {
    return (u64)f2b(a) | ((u64)f2b(b) << 16) | ((u64)f2b(c) << 32) | ((u64)f2b(d) << 48);
}
// A-operand frag flat index for element [m][c] of a 128-col operand
__device__ __forceinline__ int fidxA(int m, int c) {
    return (((m >> 4)*4 + (c >> 5))*64 + ((c >> 3) & 3)*16 + (m & 15))*8 + (c & 7);
}

// ---------------------------------------------------------------------------
// Kernel 1 (merged): blocks 0..129 = weight fuse/pack, 130..2177 = transpose.
__global__ void __launch_bounds__(512)
k_pt(const float* __restrict__ x,
     const float* __restrict__ Wq, const float* __restrict__ bq,
     const float* __restrict__ Wk, const float* __restrict__ bk,
     const float* __restrict__ Wv, const float* __restrict__ bv,
     const float* __restrict__ Wo, const float* __restrict__ bo,
     const float* __restrict__ W1, const float* __restrict__ W2,
     u16* __restrict__ Afrag, u16* __restrict__ Wovfrag,
     u16* __restrict__ W1frag, u16* __restrict__ W2frag,
     u16* __restrict__ W2Tfrag,
     float* __restrict__ bA, float* __restrict__ su,
     float* __restrict__ bov, float* __restrict__ d0,
     u16* __restrict__ xT)
{
    const int blk = blockIdx.x, tid = threadIdx.x;

    if (blk >= 130) {
        // ---- transpose x[b][c][n] -> xT[b][n][c] (bf16), 32x32 tiles ----
        __shared__ u16 tile[32][33];
        const int blk2 = blk - 130;
        const int b  = blk2 >> 10;
        const int ct = (blk2 >> 8) & 3;
        const int nt = blk2 & 255;
        const int tx = tid & 31, ty = tid >> 5;      // 32 x 16
        const size_t xb = (size_t)b * 128 * 8192;
        #pragma unroll
        for (int j = 0; j < 2; ++j) {
            int c = ct*32 + ty + j*16;
            tile[ty + j*16][tx] = f2b(x[xb + (size_t)c * 8192 + (size_t)(nt*32 + tx)]);
        }
        __syncthreads();
        #pragma unroll
        for (int j = 0; j < 2; ++j) {
            int n = nt*32 + ty + j*16;
            xT[xb + (size_t)n * 128 + (size_t)(ct*32 + tx)] = tile[tx][ty + j*16];
        }
        return;
    }

    const int i = tid & 127, p = tid >> 7;          // 4-way K-split
    if (blk < 128) {
        __shared__ float sWk[128], sWo[128];
        __shared__ float s_pA[4][128], s_pV[4][128];
        if (tid < 128) sWk[tid] = Wk[tid*128 + blk];
        else if (tid < 256) sWo[tid-128] = Wo[blk*128 + (tid-128)];
        __syncthreads();
        float accA = 0.f, accV = 0.f;
        #pragma unroll 8
        for (int o = p*32; o < p*32 + 32; ++o) {
            accA += sWk[o] * Wq[o*128 + i];
            accV += sWo[o] * Wv[o*128 + i];
        }
        s_pA[p][i] = accA; s_pV[p][i] = accV;
        __syncthreads();
        if (tid < 128) {
            float v = s_pA[0][tid] + s_pA[1][tid] + s_pA[2][tid] + s_pA[3][tid];
            Afrag[fidxA(blk, tid)] = f2b(v);
        } else if (tid < 256) {
            int ii = tid - 128;
            float v = s_pV[0][ii] + s_pV[1][ii] + s_pV[2][ii] + s_pV[3][ii];
            Wovfrag[fidxA(blk, ii)] = f2b(v);
        }
    } else if (blk == 128) {
        __shared__ float s_r[3][4][128];
        float a1 = 0.f, a2 = 0.f, a3 = 0.f;
        #pragma unroll 8
        for (int o = p*32; o < p*32 + 32; ++o) {
            a1 += Wk[o*128 + i] * bq[o];
            a2 += Wq[o*128 + i] * bk[o];
            a3 += Wo[i*128 + o] * bv[o];
        }
        s_r[0][p][i] = a1; s_r[1][p][i] = a2; s_r[2][p][i] = a3;
        __syncthreads();
        if (tid < 128) {
            bA[tid] = s_r[0][0][tid] + s_r[0][1][tid] + s_r[0][2][tid] + s_r[0][3][tid];
        } else if (tid < 256) {
            int ii = tid - 128;
            su[ii] = s_r[1][0][ii] + s_r[1][1][ii] + s_r[1][2][ii] + s_r[1][3][ii];
        } else if (tid < 384) {
            int ii = tid - 256;
            bov[ii] = s_r[2][0][ii] + s_r[2][1][ii] + s_r[2][2][ii] + s_r[2][3][ii] + bo[ii];
        } else if (tid < 448) {
            int l = tid - 384;
            float part = bq[l]*bk[l] + bq[l+64]*bk[l+64];
            part += __shfl_xor(part, 1);
            part += __shfl_xor(part, 2);
            part += __shfl_xor(part, 4);
            part += __shfl_xor(part, 8);
            part += __shfl_xor(part, 16);
            part += __shfl_xor(part, 32);
            if (l == 0) *d0 = part;
        }
    } else {
        // blk == 129: fragment packs for W1 / W2 / W2T
        for (int e = tid; e < 4096; e += 512) {
            int ii = e & 127, r2 = e >> 7;         // r2 in [0,32)
            {   // W1frag: B-operand of H=E*W1, elem B[k=ii][n=r2]
                int nt = r2 >> 4, lmm = r2 & 15;
                int ks = ii >> 5, q = (ii >> 3) & 3, j = ii & 7;
                W1frag[((nt*4 + ks)*64 + q*16 + lmm)*8 + j] = f2b(W1[ii*32 + r2]);
            }
            {   // W2frag: A-operand of G=W2*QK, elem A[m=r2][c=ii]
                int mt = r2 >> 4, lmm = r2 & 15;
                int ks = ii >> 5, q = (ii >> 3) & 3, j = ii & 7;
                W2frag[((mt*4 + ks)*64 + q*16 + lmm)*8 + j] = f2b(W2[r2*128 + ii]);
            }
            {   // W2Tfrag: A-operand of W2T*Hbar (K=32), elem A[c=ii][k=r2]
                int mt = ii >> 4, lmm = ii & 15;
                int q = r2 >> 3, j = r2 & 7;
                W2Tfrag[(mt*64 + q*16 + lmm)*8 + j] = f2b(W2[r2*128 + ii]);
            }
        }
    }
}

// ---------------------------------------------------------------------------
// Kernel 2: fused main. Grid 2048 x 256; 8 n per block; ~29 KB LDS.
__global__ void __launch_bounds__(256, 5)
k_main(const u16* __restrict__ xT, const float* __restrict__ coords,
       const int* __restrict__ idx, const float* __restrict__ Bg,
       const float* __restrict__ b1g, const float* __restrict__ b2g,
       const u16* __restrict__ Afrag, const u16* __restrict__ Wovfrag,
       const u16* __restrict__ W1frag, const u16* __restrict__ W2frag,
       const u16* __restrict__ W2Tfrag,
       const float* __restrict__ bAg, const float* __restrict__ sug,
       const float* __restrict__ bovg, const float* __restrict__ d0g,
       float* __restrict__ out)
{
    __shared__ __align__(16) u16   sH[128][40];      // H bf16 rows (n,k) x m
    __shared__ __align__(16) u16   s_qkb[8][136];    // qk bf16 [n][c]
    __shared__ __align__(16) u16   s_gb[8][40];      // g bf16 [n][m]
    __shared__ __align__(16) u16   s_wtb[8][136];    // W bf16 [n][c]
    __shared__ __align__(16) float s_xb[8][132];     // xbar+b2 f32 [n][c]
    __shared__ __align__(16) float s_del[128][4];
    __shared__ float s_sc[8][17];
    __shared__ float s_attn[8][17];
    __shared__ u16   sHbar[32][12];                  // hbar bf16 [m][n]
    __shared__ float s_e0[8];
    __shared__ __align__(16) float s_b2[128], s_su[128];
    __shared__ float s_bA[128], s_bov[128], s_b1[32];
    __shared__ __align__(16) float sBgT[64][4];
    __shared__ int s_idx[128];

    const int tid = threadIdx.x;
    const int w = tid >> 6, l = tid & 63, lm = l & 15, lq = l >> 4, lmm = lm & 7;
    const int g0 = blockIdx.x * 8;
    const int bsel = g0 >> 13;
    const int n0 = g0 & 8191;
    const size_t bbase = ((size_t)bsel) << 13;
    const float inv_sqrtC = 0.08838834764831845f;

    // ---- preamble: biases/Bg + idx/delta + QK MFMA (no LDS deps) ----
    if (tid < 128) {
        s_bA[tid] = bAg[tid]; s_su[tid] = sug[tid];
        s_bov[tid] = bovg[tid]; s_b2[tid] = b2g[tid];
    } else if (tid < 160) {
        s_b1[tid-128] = b1g[tid-128];
    }
    sBgT[tid >> 2][tid & 3] = Bg[(tid & 3)*64 + (tid >> 2)];
    const float c_d0 = *d0g;

    if (tid < 128) {
        int j = idx[(size_t)g0*16 + tid];
        s_idx[tid] = j;
        float4 cj = *(const float4*)&coords[(size_t)(bbase + j)*4];
        float4 cn = *(const float4*)&coords[(size_t)(g0 + (tid >> 4))*4];
        *(float4*)s_del[tid] = make_float4(cj.x-cn.x, cj.y-cn.y, cj.z-cn.z, cj.w-cn.w);
    }
    // QK = A*X (cols n = lm&7 duplicated; only lm<8 stored)
    f32x4 accq[2] = {{0.f,0.f,0.f,0.f},{0.f,0.f,0.f,0.f}};
    {
        const bf16x8* Af = (const bf16x8*)Afrag;
        bf16x8 bfr[4];
        #pragma unroll
        for (int ks = 0; ks < 4; ++ks)
            bfr[ks] = *(const bf16x8*)&xT[(((size_t)(g0 + lmm)) << 7) + ks*32 + lq*8];
        #pragma unroll
        for (int mi = 0; mi < 2; ++mi) {
            const int ct = w*2 + mi;
            #pragma unroll
            for (int ks = 0; ks < 4; ++ks) {
                bf16x8 a = Af[(ct*4 + ks)*64 + l];
                accq[mi] = __builtin_amdgcn_mfma_f32_16x16x32_bf16(a, bfr[ks], accq[mi], 0, 0, 0);
            }
        }
    }
    __syncthreads();   // B1

    if (lm < 8) {
        #pragma unroll
        for (int mi = 0; mi < 2; ++mi) {
            int c0 = (w*2 + mi)*16 + lq*4;
            *(u64*)&s_qkb[lm][c0] = pack4(accq[mi][0] + s_bA[c0],   accq[mi][1] + s_bA[c0+1],
                                          accq[mi][2] + s_bA[c0+2], accq[mi][3] + s_bA[c0+3]);
        }
    }
    __syncthreads();   // B2

    // ---- H = relu(E*W1+b1) [all waves] ; G = W2*QK [w0-1] ; e0t0 [w2-3] ----
    {
        const bf16x8* W1f = (const bf16x8*)W1frag;
        bf16x8 w1f[2][4];
        #pragma unroll
        for (int nt = 0; nt < 2; ++nt)
            #pragma unroll
            for (int ks = 0; ks < 4; ++ks) w1f[nt][ks] = W1f[(nt*4 + ks)*64 + l];
        #pragma unroll
        for (int mi = 0; mi < 2; ++mi) {
            const int mt = w*2 + mi;               // mt = n, lm = k
            float4 d = *(const float4*)s_del[mt*16 + lm];
            bf16x8 ea[4];
            #pragma unroll
            for (int ksp = 0; ksp < 2; ++ksp) {
                #pragma unroll
                for (int jp = 0; jp < 4; ++jp) {
                    int f = ksp*32 + lq*8 + jp*2;
                    float4 ga = *(const float4*)sBgT[f];
                    float4 gb = *(const float4*)sBgT[f+1];
                    float p0 = d.x*ga.x + d.y*ga.y + d.z*ga.z + d.w*ga.w;
                    float p1 = d.x*gb.x + d.y*gb.y + d.z*gb.z + d.w*gb.w;
                    p0 -= floorf(p0); p1 -= floorf(p1);
                    ((u32*)&ea[ksp])[jp]   = (u32)f2b(__builtin_amdgcn_sinf(p0))
                                           | ((u32)f2b(__builtin_amdgcn_sinf(p1)) << 16);
                    ((u32*)&ea[ksp+2])[jp] = (u32)f2b(__builtin_amdgcn_cosf(p0))
                                           | ((u32)f2b(__builtin_amdgcn_cosf(p1)) << 16);
                }
            }
            f32x4 acch[2] = {{0.f,0.f,0.f,0.f},{0.f,0.f,0.f,0.f}};
            #pragma unroll
            for (int ks = 0; ks < 4; ++ks) {
                acch[0] = __builtin_amdgcn_mfma_f32_16x16x32_bf16(ea[ks], w1f[0][ks], acch[0], 0,0,0);
                acch[1] = __builtin_amdgcn_mfma_f32_16x16x32_bf16(ea[ks], w1f[1][ks], acch[1], 0,0,0);
            }
            #pragma unroll
            for (int nt = 0; nt < 2; ++nt) {
                float b1v = s_b1[nt*16 + lm];
                #pragma unroll
                for (int r = 0; r < 4; ++r)
                    sH[mt*16 + lq*4 + r][nt*16 + lm] = f2b(fmaxf(acch[nt][r] + b1v, 0.f));
            }
        }
    }
    if (w < 2) {
        // G = W2*QK (m-tile = w)
        const bf16x8* W2f = (const bf16x8*)W2frag;
        f32x4 accg = {0.f,0.f,0.f,0.f};
        #pragma unroll
        for (int ks = 0; ks < 4; ++ks) {
            bf16x8 a = W2f[(w*4 + ks)*64 + l];
            bf16x8 bv = *(const bf16x8*)&s_qkb[lmm][ks*32 + lq*8];
            accg = __builtin_amdgcn_mfma_f32_16x16x32_bf16(a, bv, accg, 0, 0, 0);
        }
        if (lm < 8) {
            int m0 = w*16 + lq*4;
            *(u64*)&s_gb[lm][m0] = pack4(accg[0], accg[1], accg[2], accg[3]);
        }
    } else {
        int t = tid - 128;
        if (t < 64) {   // e0t0[n] = qk·b2 + x_n·su + d0
            int n = t >> 3, sub = t & 7, c0 = sub*16;
            uint4 q0 = *(const uint4*)&s_qkb[n][c0];
            uint4 q1 = *(const uint4*)&s_qkb[n][c0+8];
            uint4 x0 = *(const uint4*)&xT[(((size_t)(g0 + n)) << 7) + c0];
            uint4 x1 = *(const uint4*)&xT[(((size_t)(g0 + n)) << 7) + c0 + 8];
            float part = dot8(q0, &s_b2[c0]) + dot8(q1, &s_b2[c0+8])
                       + dot8(x0, &s_su[c0]) + dot8(x1, &s_su[c0+8]);
            part += __shfl_xor(part, 1);
            part += __shfl_xor(part, 2);
            part += __shfl_xor(part, 4);
            if (sub == 0) s_e0[n] = part + c_d0;
        }
    }
    __syncthreads();   // B3

    // ---- scores: S = [Xnb | H] · [qk ; g]; Xnb A-frags from GLOBAL ----
    {
        bf16x8 bq4[5];
        #pragma unroll
        for (int ks = 0; ks < 4; ++ks) bq4[ks] = *(const bf16x8*)&s_qkb[lmm][ks*32 + lq*8];
        bq4[4] = *(const bf16x8*)&s_gb[lmm][lq*8];
        #pragma unroll
        for (int mi = 0; mi < 2; ++mi) {
            const int mt = w*2 + mi;               // mt = n, lm = k
            const size_t rb = ((size_t)(bbase + s_idx[mt*16 + lm])) << 7;
            f32x4 acc = {0.f,0.f,0.f,0.f};
            #pragma unroll
            for (int ks = 0; ks < 4; ++ks) {
                bf16x8 a = *(const bf16x8*)&xT[rb + ks*32 + lq*8];
                acc = __builtin_amdgcn_mfma_f32_16x16x32_bf16(a, bq4[ks], acc, 0, 0, 0);
            }
            {
                bf16x8 a = *(const bf16x8*)&sH[mt*16 + lm][lq*8];
                acc = __builtin_amdgcn_mfma_f32_16x16x32_bf16(a, bq4[4], acc, 0, 0, 0);
            }
            if (lm == mt) {
                #pragma unroll
                for (int r = 0; r < 4; ++r) s_sc[mt][lq*4 + r] = acc[r];
            }
        }
    }
    __syncthreads();   // B4

    // ---- softmax over K=16 ----
    if (tid < 128) {
        int n = tid >> 4, k = tid & 15;
        float s = (s_sc[n][k] + s_e0[n]) * inv_sqrtC;
        float mx = s;
        mx = fmaxf(mx, __shfl_xor(mx, 1, 16));
        mx = fmaxf(mx, __shfl_xor(mx, 2, 16));
        mx = fmaxf(mx, __shfl_xor(mx, 4, 16));
        mx = fmaxf(mx, __shfl_xor(mx, 8, 16));
        float ex = __expf(s - mx);
        float sm = ex;
        sm += __shfl_xor(sm, 1, 16);
        sm += __shfl_xor(sm, 2, 16);
        sm += __shfl_xor(sm, 4, 16);
        sm += __shfl_xor(sm, 8, 16);
        s_attn[n][k] = ex / sm;
    }
    __syncthreads();   // B5

    // ---- xbar (+b2) from GLOBAL re-gather -> s_xb ; hbar -> sHbar ----
    {
        int n = tid >> 5, cs = tid & 31, c0 = cs*4;
        float a0[16];
        #pragma unroll
        for (int k = 0; k < 16; ++k) a0[k] = s_attn[n][k];
        float4 facc = *(const float4*)&s_b2[c0];
        #pragma unroll
        for (int k = 0; k < 16; ++k) {
            uint2 v = *(const uint2*)&xT[(((size_t)(bbase + s_idx[n*16 + k])) << 7) + c0];
            facc.x += a0[k]*bl(v.x); facc.y += a0[k]*bh(v.x);
            facc.z += a0[k]*bl(v.y); facc.w += a0[k]*bh(v.y);
        }
        *(float4*)&s_xb[n][c0] = facc;
        int m = cs;
        float hacc = 0.f;
        #pragma unroll
        for (int k = 0; k < 16; ++k) hacc += a0[k] * b2f(sH[n*16 + k][m]);
        sHbar[m][n] = f2b(hacc);
    }
    __syncthreads();   // B6

    // ---- W = xbar + W2T*Hbar -> bf16 [n][c] ----
    {
        const bf16x8* W2Tf = (const bf16x8*)W2Tfrag;
        bf16x8 bv;
        #pragma unroll
        for (int j = 0; j < 8; ++j) bv[j] = (short)sHbar[lq*8 + j][lmm];
        #pragma unroll
        for (int mi = 0; mi < 2; ++mi) {
            const int mt = w*2 + mi;
            bf16x8 a = W2Tf[mt*64 + l];
            f32x4 accw = {0.f,0.f,0.f,0.f};
            accw = __builtin_amdgcn_mfma_f32_16x16x32_bf16(a, bv, accw, 0, 0, 0);
            if (lm < 8) {
                int c0 = mt*16 + lq*4;
                float4 xb4 = *(const float4*)&s_xb[lm][c0];
                *(u64*)&s_wtb[lm][c0] = pack4(xb4.x + accw[0], xb4.y + accw[1],
                                              xb4.z + accw[2], xb4.w + accw[3]);
            }
        }
    }
    __syncthreads();   // B7

    // ---- OUT = Wov*W + bov -> global ----
    {
        const bf16x8* Wvf = (const bf16x8*)Wovfrag;
        bf16x8 bv[4];
        #pragma unroll
        for (int ks = 0; ks < 4; ++ks) bv[ks] = *(const bf16x8*)&s_wtb[lmm][ks*32 + lq*8];
        #pragma unroll
        for (int mi = 0; mi < 2; ++mi) {
            const int ct = w*2 + mi;
            f32x4 acco = {0.f,0.f,0.f,0.f};
            #pragma unroll
            for (int ks = 0; ks < 4; ++ks) {
                bf16x8 a = Wvf[(ct*4 + ks)*64 + l];
                acco = __builtin_amdgcn_mfma_f32_16x16x32_bf16(a, bv[ks], acco, 0, 0, 0);
            }
            if (lm < 8) {
                #pragma unroll
                for (int r = 0; r < 4; ++r) {
                    int o = ct*16 + lq*4 + r;
                    out[(((size_t)(bsel*128 + o)) << 13) + n0 + lm] = acco[r] + s_bov[o];
                }
            }
        }
    }
}

// ---------------------------------------------------------------------------
extern "C" void kernel_launch(void* const* d_in, const int* in_sizes, int n_in,
                              void* d_out, int out_size, void* d_ws, size_t ws_size,
                              hipStream_t stream)
{
    const float* x      = (const float*)d_in[0];
    const float* coords = (const float*)d_in[1];
    const int*   idx    = (const int*)d_in[2];
    const float* Bg     = (const float*)d_in[3];
    const float* W1     = (const float*)d_in[4];
    const float* b1     = (const float*)d_in[5];
    const float* W2     = (const float*)d_in[6];
    const float* b2     = (const float*)d_in[7];
    const float* Wq     = (const float*)d_in[8];
    const float* bq     = (const float*)d_in[9];
    const float* Wk     = (const float*)d_in[10];
    const float* bk     = (const float*)d_in[11];
    const float* Wv     = (const float*)d_in[12];
    const float* bv     = (const float*)d_in[13];
    const float* Wo     = (const float*)d_in[14];
    const float* bo     = (const float*)d_in[15];
    float* out = (float*)d_out;

    char* ws = (char*)d_ws;
    u16*   Afrag   = (u16*)(ws);              // 32768 B
    u16*   Wovfrag = (u16*)(ws + 32768);      // 32768 B
    u16*   W1frag  = (u16*)(ws + 65536);      // 8192 B
    u16*   W2frag  = (u16*)(ws + 73728);      // 8192 B
    u16*   W2Tfrag = (u16*)(ws + 81920);      // 8192 B
    float* bA      = (float*)(ws + 90112);    // 512 B
    float* su      = (float*)(ws + 90624);    // 512 B
    float* bov     = (float*)(ws + 91136);    // 512 B
    float* d0      = (float*)(ws + 91648);    // 16 B
    u16*   xT      = (u16*)(ws + 94208);      // 4 MiB

    k_pt<<<2178, 512, 0, stream>>>(x, Wq, bq, Wk, bk, Wv, bv, Wo, bo, W1, W2,
                                   Afrag, Wovfrag, W1frag, W2frag, W2Tfrag,
                                   bA, su, bov, d0, xT);
    k_main<<<2048, 256, 0, stream>>>(xT, coords, idx, Bg, b1, b2,
                                     Afrag, Wovfrag, W1frag, W2frag, W2Tfrag,
                                     bA, su, bov, d0, out);
}

// Round 6
// 128.933 us; speedup vs baseline: 1.4888x; 1.4888x over previous
//
#include <hip/hip_runtime.h>

// LSGA fused kernel, round 6: round-5 structure with the spill fixed.
// __launch_bounds__(256,5) had capped VGPRs at 48 -> massive scratch traffic
// (WRITE_SIZE 208 MB). Now (256,4): VGPR cap 128 (no spill), 4 blocks/CU.
//
// Algebra (exact given sum(attn)=1):
//   qk   = A·x_n + bA,            A = Wk^T Wq, bA = Wk^T bq          [128]
//   s[k] = (qk·x_nb[k] + h[k]·g + qk·b2 + x_n·u + bq·bk)/sqrt(C)
//          g = W2·qk [32], u = Wq^T bk, h[k] = relu(E[k]·W1 + b1)
//   attn = softmax_k(s)
//   w    = sum_k attn[k]*x_nb[k] + W2^T·(sum_k attn[k]*h[k]) + b2    [128]
//   out  = Wov·w + bov,           Wov = Wo·Wv, bov = Wo·bv + bo
//
// MFMA 16x16x32 lane mappings (verified rounds 3/4/5):
//   A-frag:  A[m = lane&15][k = (lane>>4)*8 + j]
//   B-frag:  B[k = (lane>>4)*8 + j][n = lane&15]
//   C/D:     col = lane&15, row = (lane>>4)*4 + reg

using u16 = unsigned short;
using u32 = unsigned int;
using u64 = unsigned long long;

typedef short bf16x8 __attribute__((ext_vector_type(8)));
typedef float f32x4  __attribute__((ext_vector_type(4)));

__device__ __forceinline__ float bl(u32 u) { return __uint_as_float(u << 16); }
__device__ __forceinline__ float bh(u32 u) { return __uint_as_float(u & 0xffff0000u); }
__device__ __forceinline__ float b2f(u16 u) { return __uint_as_float(((u32)u) << 16); }
__device__ __forceinline__ u16 f2b(float f) {
    u32 u = __float_as_uint(f);
    u32 r = u + 0x7fffu + ((u >> 16) & 1u);   // RNE
    return (u16)(r >> 16);
}
__device__ __forceinline__ float dot8(uint4 wv, const float* xp) {
    float4 a = *(const float4*)xp;
    float4 b = *(const float4*)(xp + 4);
    return bl(wv.x)*a.x + bh(wv.x)*a.y + bl(wv.y)*a.z + bh(wv.y)*a.w
         + bl(wv.z)*b.x + bh(wv.z)*b.y + bl(wv.w)*b.z + bh(wv.w)*b.w;
}
__device__ __forceinline__ u64 pack4(float a, float b, float c, float d) {
    return (u64)f2b(a) | ((u64)f2b(b) << 16) | ((u64)f2b(c) << 32) | ((u64)f2b(d) << 48);
}
// A-operand frag flat index for element [m][c] of a 128-col operand
__device__ __forceinline__ int fidxA(int m, int c) {
    return (((m >> 4)*4 + (c >> 5))*64 + ((c >> 3) & 3)*16 + (m & 15))*8 + (c & 7);
}

// ---------------------------------------------------------------------------
// Kernel 1 (merged): blocks 0..129 = weight fuse/pack, 130..2177 = transpose.
__global__ void __launch_bounds__(512)
k_pt(const float* __restrict__ x,
     const float* __restrict__ Wq, const float* __restrict__ bq,
     const float* __restrict__ Wk, const float* __restrict__ bk,
     const float* __restrict__ Wv, const float* __restrict__ bv,
     const float* __restrict__ Wo, const float* __restrict__ bo,
     const float* __restrict__ W1, const float* __restrict__ W2,
     u16* __restrict__ Afrag, u16* __restrict__ Wovfrag,
     u16* __restrict__ W1frag, u16* __restrict__ W2frag,
     u16* __restrict__ W2Tfrag,
     float* __restrict__ bA, float* __restrict__ su,
     float* __restrict__ bov, float* __restrict__ d0,
     u16* __restrict__ xT)
{
    const int blk = blockIdx.x, tid = threadIdx.x;

    if (blk >= 130) {
        // ---- transpose x[b][c][n] -> xT[b][n][c] (bf16), 32x32 tiles ----
        __shared__ u16 tile[32][33];
        const int blk2 = blk - 130;
        const int b  = blk2 >> 10;
        const int ct = (blk2 >> 8) & 3;
        const int nt = blk2 & 255;
        const int tx = tid & 31, ty = tid >> 5;      // 32 x 16
        const size_t xb = (size_t)b * 128 * 8192;
        #pragma unroll
        for (int j = 0; j < 2; ++j) {
            int c = ct*32 + ty + j*16;
            tile[ty + j*16][tx] = f2b(x[xb + (size_t)c * 8192 + (size_t)(nt*32 + tx)]);
        }
        __syncthreads();
        #pragma unroll
        for (int j = 0; j < 2; ++j) {
            int n = nt*32 + ty + j*16;
            xT[xb + (size_t)n * 128 + (size_t)(ct*32 + tx)] = tile[tx][ty + j*16];
        }
        return;
    }

    const int i = tid & 127, p = tid >> 7;          // 4-way K-split
    if (blk < 128) {
        __shared__ float sWk[128], sWo[128];
        __shared__ float s_pA[4][128], s_pV[4][128];
        if (tid < 128) sWk[tid] = Wk[tid*128 + blk];
        else if (tid < 256) sWo[tid-128] = Wo[blk*128 + (tid-128)];
        __syncthreads();
        float accA = 0.f, accV = 0.f;
        #pragma unroll 8
        for (int o = p*32; o < p*32 + 32; ++o) {
            accA += sWk[o] * Wq[o*128 + i];
            accV += sWo[o] * Wv[o*128 + i];
        }
        s_pA[p][i] = accA; s_pV[p][i] = accV;
        __syncthreads();
        if (tid < 128) {
            float v = s_pA[0][tid] + s_pA[1][tid] + s_pA[2][tid] + s_pA[3][tid];
            Afrag[fidxA(blk, tid)] = f2b(v);
        } else if (tid < 256) {
            int ii = tid - 128;
            float v = s_pV[0][ii] + s_pV[1][ii] + s_pV[2][ii] + s_pV[3][ii];
            Wovfrag[fidxA(blk, ii)] = f2b(v);
        }
    } else if (blk == 128) {
        __shared__ float s_r[3][4][128];
        float a1 = 0.f, a2 = 0.f, a3 = 0.f;
        #pragma unroll 8
        for (int o = p*32; o < p*32 + 32; ++o) {
            a1 += Wk[o*128 + i] * bq[o];
            a2 += Wq[o*128 + i] * bk[o];
            a3 += Wo[i*128 + o] * bv[o];
        }
        s_r[0][p][i] = a1; s_r[1][p][i] = a2; s_r[2][p][i] = a3;
        __syncthreads();
        if (tid < 128) {
            bA[tid] = s_r[0][0][tid] + s_r[0][1][tid] + s_r[0][2][tid] + s_r[0][3][tid];
        } else if (tid < 256) {
            int ii = tid - 128;
            su[ii] = s_r[1][0][ii] + s_r[1][1][ii] + s_r[1][2][ii] + s_r[1][3][ii];
        } else if (tid < 384) {
            int ii = tid - 256;
            bov[ii] = s_r[2][0][ii] + s_r[2][1][ii] + s_r[2][2][ii] + s_r[2][3][ii] + bo[ii];
        } else if (tid < 448) {
            int l = tid - 384;
            float part = bq[l]*bk[l] + bq[l+64]*bk[l+64];
            part += __shfl_xor(part, 1);
            part += __shfl_xor(part, 2);
            part += __shfl_xor(part, 4);
            part += __shfl_xor(part, 8);
            part += __shfl_xor(part, 16);
            part += __shfl_xor(part, 32);
            if (l == 0) *d0 = part;
        }
    } else {
        // blk == 129: fragment packs for W1 / W2 / W2T
        for (int e = tid; e < 4096; e += 512) {
            int ii = e & 127, r2 = e >> 7;         // r2 in [0,32)
            {   // W1frag: B-operand of H=E*W1, elem B[k=ii][n=r2]
                int nt = r2 >> 4, lmm = r2 & 15;
                int ks = ii >> 5, q = (ii >> 3) & 3, j = ii & 7;
                W1frag[((nt*4 + ks)*64 + q*16 + lmm)*8 + j] = f2b(W1[ii*32 + r2]);
            }
            {   // W2frag: A-operand of G=W2*QK, elem A[m=r2][c=ii]
                int mt = r2 >> 4, lmm = r2 & 15;
                int ks = ii >> 5, q = (ii >> 3) & 3, j = ii & 7;
                W2frag[((mt*4 + ks)*64 + q*16 + lmm)*8 + j] = f2b(W2[r2*128 + ii]);
            }
            {   // W2Tfrag: A-operand of W2T*Hbar (K=32), elem A[c=ii][k=r2]
                int mt = ii >> 4, lmm = ii & 15;
                int q = r2 >> 3, j = r2 & 7;
                W2Tfrag[(mt*64 + q*16 + lmm)*8 + j] = f2b(W2[r2*128 + ii]);
            }
        }
    }
}

// ---------------------------------------------------------------------------
// Kernel 2: fused main. Grid 2048 x 256; 8 n per block; ~27 KB LDS.
// (256,4): VGPR cap 128 -> no spill; 4 blocks/CU resident.
__global__ void __launch_bounds__(256, 4)
k_main(const u16* __restrict__ xT, const float* __restrict__ coords,
       const int* __restrict__ idx, const float* __restrict__ Bg,
       const float* __restrict__ b1g, const float* __restrict__ b2g,
       const u16* __restrict__ Afrag, const u16* __restrict__ Wovfrag,
       const u16* __restrict__ W1frag, const u16* __restrict__ W2frag,
       const u16* __restrict__ W2Tfrag,
       const float* __restrict__ bAg, const float* __restrict__ sug,
       const float* __restrict__ bovg, const float* __restrict__ d0g,
       float* __restrict__ out)
{
    __shared__ __align__(16) u16   sH[128][40];      // H bf16 rows (n,k) x m
    __shared__ __align__(16) u16   s_qkb[8][136];    // qk bf16 [n][c]
    __shared__ __align__(16) u16   s_gb[8][40];      // g bf16 [n][m]
    __shared__ __align__(16) u16   s_wtb[8][136];    // W bf16 [n][c]
    __shared__ __align__(16) float s_xb[8][132];     // xbar+b2 f32 [n][c]
    __shared__ __align__(16) float s_del[128][4];
    __shared__ float s_sc[8][17];
    __shared__ float s_attn[8][17];
    __shared__ u16   sHbar[32][12];                  // hbar bf16 [m][n]
    __shared__ float s_e0[8];
    __shared__ __align__(16) float s_b2[128], s_su[128];
    __shared__ float s_bA[128], s_bov[128], s_b1[32];
    __shared__ __align__(16) float sBgT[64][4];
    __shared__ int s_idx[128];

    const int tid = threadIdx.x;
    const int w = tid >> 6, l = tid & 63, lm = l & 15, lq = l >> 4, lmm = lm & 7;
    const int g0 = blockIdx.x * 8;
    const int bsel = g0 >> 13;
    const int n0 = g0 & 8191;
    const size_t bbase = ((size_t)bsel) << 13;
    const float inv_sqrtC = 0.08838834764831845f;

    // ---- preamble: biases/Bg + idx/delta + QK MFMA (no LDS deps) ----
    if (tid < 128) {
        s_bA[tid] = bAg[tid]; s_su[tid] = sug[tid];
        s_bov[tid] = bovg[tid]; s_b2[tid] = b2g[tid];
    } else if (tid < 160) {
        s_b1[tid-128] = b1g[tid-128];
    }
    sBgT[tid >> 2][tid & 3] = Bg[(tid & 3)*64 + (tid >> 2)];
    const float c_d0 = *d0g;

    if (tid < 128) {
        int j = idx[(size_t)g0*16 + tid];
        s_idx[tid] = j;
        float4 cj = *(const float4*)&coords[(size_t)(bbase + j)*4];
        float4 cn = *(const float4*)&coords[(size_t)(g0 + (tid >> 4))*4];
        *(float4*)s_del[tid] = make_float4(cj.x-cn.x, cj.y-cn.y, cj.z-cn.z, cj.w-cn.w);
    }
    // QK = A*X (cols n = lm&7 duplicated; only lm<8 stored)
    f32x4 accq[2] = {{0.f,0.f,0.f,0.f},{0.f,0.f,0.f,0.f}};
    {
        const bf16x8* Af = (const bf16x8*)Afrag;
        bf16x8 bfr[4];
        #pragma unroll
        for (int ks = 0; ks < 4; ++ks)
            bfr[ks] = *(const bf16x8*)&xT[(((size_t)(g0 + lmm)) << 7) + ks*32 + lq*8];
        #pragma unroll
        for (int mi = 0; mi < 2; ++mi) {
            const int ct = w*2 + mi;
            #pragma unroll
            for (int ks = 0; ks < 4; ++ks) {
                bf16x8 a = Af[(ct*4 + ks)*64 + l];
                accq[mi] = __builtin_amdgcn_mfma_f32_16x16x32_bf16(a, bfr[ks], accq[mi], 0, 0, 0);
            }
        }
    }
    __syncthreads();   // B1

    if (lm < 8) {
        #pragma unroll
        for (int mi = 0; mi < 2; ++mi) {
            int c0 = (w*2 + mi)*16 + lq*4;
            *(u64*)&s_qkb[lm][c0] = pack4(accq[mi][0] + s_bA[c0],   accq[mi][1] + s_bA[c0+1],
                                          accq[mi][2] + s_bA[c0+2], accq[mi][3] + s_bA[c0+3]);
        }
    }
    __syncthreads();   // B2

    // ---- H = relu(E*W1+b1) [all waves] ; G = W2*QK [w0-1] ; e0t0 [w2-3] ----
    {
        const bf16x8* W1f = (const bf16x8*)W1frag;
        bf16x8 w1f[2][4];
        #pragma unroll
        for (int nt = 0; nt < 2; ++nt)
            #pragma unroll
            for (int ks = 0; ks < 4; ++ks) w1f[nt][ks] = W1f[(nt*4 + ks)*64 + l];
        #pragma unroll
        for (int mi = 0; mi < 2; ++mi) {
            const int mt = w*2 + mi;               // mt = n, lm = k
            float4 d = *(const float4*)s_del[mt*16 + lm];
            bf16x8 ea[4];
            #pragma unroll
            for (int ksp = 0; ksp < 2; ++ksp) {
                #pragma unroll
                for (int jp = 0; jp < 4; ++jp) {
                    int f = ksp*32 + lq*8 + jp*2;
                    float4 ga = *(const float4*)sBgT[f];
                    float4 gb = *(const float4*)sBgT[f+1];
                    float p0 = d.x*ga.x + d.y*ga.y + d.z*ga.z + d.w*ga.w;
                    float p1 = d.x*gb.x + d.y*gb.y + d.z*gb.z + d.w*gb.w;
                    p0 -= floorf(p0); p1 -= floorf(p1);
                    ((u32*)&ea[ksp])[jp]   = (u32)f2b(__builtin_amdgcn_sinf(p0))
                                           | ((u32)f2b(__builtin_amdgcn_sinf(p1)) << 16);
                    ((u32*)&ea[ksp+2])[jp] = (u32)f2b(__builtin_amdgcn_cosf(p0))
                                           | ((u32)f2b(__builtin_amdgcn_cosf(p1)) << 16);
                }
            }
            f32x4 acch[2] = {{0.f,0.f,0.f,0.f},{0.f,0.f,0.f,0.f}};
            #pragma unroll
            for (int ks = 0; ks < 4; ++ks) {
                acch[0] = __builtin_amdgcn_mfma_f32_16x16x32_bf16(ea[ks], w1f[0][ks], acch[0], 0,0,0);
                acch[1] = __builtin_amdgcn_mfma_f32_16x16x32_bf16(ea[ks], w1f[1][ks], acch[1], 0,0,0);
            }
            #pragma unroll
            for (int nt = 0; nt < 2; ++nt) {
                float b1v = s_b1[nt*16 + lm];
                #pragma unroll
                for (int r = 0; r < 4; ++r)
                    sH[mt*16 + lq*4 + r][nt*16 + lm] = f2b(fmaxf(acch[nt][r] + b1v, 0.f));
            }
        }
    }
    if (w < 2) {
        // G = W2*QK (m-tile = w)
        const bf16x8* W2f = (const bf16x8*)W2frag;
        f32x4 accg = {0.f,0.f,0.f,0.f};
        #pragma unroll
        for (int ks = 0; ks < 4; ++ks) {
            bf16x8 a = W2f[(w*4 + ks)*64 + l];
            bf16x8 bv = *(const bf16x8*)&s_qkb[lmm][ks*32 + lq*8];
            accg = __builtin_amdgcn_mfma_f32_16x16x32_bf16(a, bv, accg, 0, 0, 0);
        }
        if (lm < 8) {
            int m0 = w*16 + lq*4;
            *(u64*)&s_gb[lm][m0] = pack4(accg[0], accg[1], accg[2], accg[3]);
        }
    } else {
        int t = tid - 128;
        if (t < 64) {   // e0t0[n] = qk·b2 + x_n·su + d0
            int n = t >> 3, sub = t & 7, c0 = sub*16;
            uint4 q0 = *(const uint4*)&s_qkb[n][c0];
            uint4 q1 = *(const uint4*)&s_qkb[n][c0+8];
            uint4 x0 = *(const uint4*)&xT[(((size_t)(g0 + n)) << 7) + c0];
            uint4 x1 = *(const uint4*)&xT[(((size_t)(g0 + n)) << 7) + c0 + 8];
            float part = dot8(q0, &s_b2[c0]) + dot8(q1, &s_b2[c0+8])
                       + dot8(x0, &s_su[c0]) + dot8(x1, &s_su[c0+8]);
            part += __shfl_xor(part, 1);
            part += __shfl_xor(part, 2);
            part += __shfl_xor(part, 4);
            if (sub == 0) s_e0[n] = part + c_d0;
        }
    }
    __syncthreads();   // B3

    // ---- scores: S = [Xnb | H] · [qk ; g]; Xnb A-frags from GLOBAL ----
    {
        bf16x8 bq4[5];
        #pragma unroll
        for (int ks = 0; ks < 4; ++ks) bq4[ks] = *(const bf16x8*)&s_qkb[lmm][ks*32 + lq*8];
        bq4[4] = *(const bf16x8*)&s_gb[lmm][lq*8];
        #pragma unroll
        for (int mi = 0; mi < 2; ++mi) {
            const int mt = w*2 + mi;               // mt = n, lm = k
            const size_t rb = ((size_t)(bbase + s_idx[mt*16 + lm])) << 7;
            f32x4 acc = {0.f,0.f,0.f,0.f};
            #pragma unroll
            for (int ks = 0; ks < 4; ++ks) {
                bf16x8 a = *(const bf16x8*)&xT[rb + ks*32 + lq*8];
                acc = __builtin_amdgcn_mfma_f32_16x16x32_bf16(a, bq4[ks], acc, 0, 0, 0);
            }
            {
                bf16x8 a = *(const bf16x8*)&sH[mt*16 + lm][lq*8];
                acc = __builtin_amdgcn_mfma_f32_16x16x32_bf16(a, bq4[4], acc, 0, 0, 0);
            }
            if (lm == mt) {
                #pragma unroll
                for (int r = 0; r < 4; ++r) s_sc[mt][lq*4 + r] = acc[r];
            }
        }
    }
    __syncthreads();   // B4

    // ---- softmax over K=16 ----
    if (tid < 128) {
        int n = tid >> 4, k = tid & 15;
        float s = (s_sc[n][k] + s_e0[n]) * inv_sqrtC;
        float mx = s;
        mx = fmaxf(mx, __shfl_xor(mx, 1, 16));
        mx = fmaxf(mx, __shfl_xor(mx, 2, 16));
        mx = fmaxf(mx, __shfl_xor(mx, 4, 16));
        mx = fmaxf(mx, __shfl_xor(mx, 8, 16));
        float ex = __expf(s - mx);
        float sm = ex;
        sm += __shfl_xor(sm, 1, 16);
        sm += __shfl_xor(sm, 2, 16);
        sm += __shfl_xor(sm, 4, 16);
        sm += __shfl_xor(sm, 8, 16);
        s_attn[n][k] = ex / sm;
    }
    __syncthreads();   // B5

    // ---- xbar (+b2) from GLOBAL re-gather -> s_xb ; hbar -> sHbar ----
    {
        int n = tid >> 5, cs = tid & 31, c0 = cs*4;
        float a0[16];
        #pragma unroll
        for (int k = 0; k < 16; ++k) a0[k] = s_attn[n][k];
        float4 facc = *(const float4*)&s_b2[c0];
        #pragma unroll
        for (int k = 0; k < 16; ++k) {
            uint2 v = *(const uint2*)&xT[(((size_t)(bbase + s_idx[n*16 + k])) << 7) + c0];
            facc.x += a0[k]*bl(v.x); facc.y += a0[k]*bh(v.x);
            facc.z += a0[k]*bl(v.y); facc.w += a0[k]*bh(v.y);
        }
        *(float4*)&s_xb[n][c0] = facc;
        int m = cs;
        float hacc = 0.f;
        #pragma unroll
        for (int k = 0; k < 16; ++k) hacc += a0[k] * b2f(sH[n*16 + k][m]);
        sHbar[m][n] = f2b(hacc);
    }
    __syncthreads();   // B6

    // ---- W = xbar + W2T*Hbar -> bf16 [n][c] ----
    {
        const bf16x8* W2Tf = (const bf16x8*)W2Tfrag;
        bf16x8 bv;
        #pragma unroll
        for (int j = 0; j < 8; ++j) bv[j] = (short)sHbar[lq*8 + j][lmm];
        #pragma unroll
        for (int mi = 0; mi < 2; ++mi) {
            const int mt = w*2 + mi;
            bf16x8 a = W2Tf[mt*64 + l];
            f32x4 accw = {0.f,0.f,0.f,0.f};
            accw = __builtin_amdgcn_mfma_f32_16x16x32_bf16(a, bv, accw, 0, 0, 0);
            if (lm < 8) {
                int c0 = mt*16 + lq*4;
                float4 xb4 = *(const float4*)&s_xb[lm][c0];
                *(u64*)&s_wtb[lm][c0] = pack4(xb4.x + accw[0], xb4.y + accw[1],
                                              xb4.z + accw[2], xb4.w + accw[3]);
            }
        }
    }
    __syncthreads();   // B7

    // ---- OUT = Wov*W + bov -> global ----
    {
        const bf16x8* Wvf = (const bf16x8*)Wovfrag;
        bf16x8 bv[4];
        #pragma unroll
        for (int ks = 0; ks < 4; ++ks) bv[ks] = *(const bf16x8*)&s_wtb[lmm][ks*32 + lq*8];
        #pragma unroll
        for (int mi = 0; mi < 2; ++mi) {
            const int ct = w*2 + mi;
            f32x4 acco = {0.f,0.f,0.f,0.f};
            #pragma unroll
            for (int ks = 0; ks < 4; ++ks) {
                bf16x8 a = Wvf[(ct*4 + ks)*64 + l];
                acco = __builtin_amdgcn_mfma_f32_16x16x32_bf16(a, bv[ks], acco, 0, 0, 0);
            }
            if (lm < 8) {
                #pragma unroll
                for (int r = 0; r < 4; ++r) {
                    int o = ct*16 + lq*4 + r;
                    out[(((size_t)(bsel*128 + o)) << 13) + n0 + lm] = acco[r] + s_bov[o];
                }
            }
        }
    }
}

// ---------------------------------------------------------------------------
extern "C" void kernel_launch(void* const* d_in, const int* in_sizes, int n_in,
                              void* d_out, int out_size, void* d_ws, size_t ws_size,
                              hipStream_t stream)
{
    const float* x      = (const float*)d_in[0];
    const float* coords = (const float*)d_in[1];
    const int*   idx    = (const int*)d_in[2];
    const float* Bg     = (const float*)d_in[3];
    const float* W1     = (const float*)d_in[4];
    const float* b1     = (const float*)d_in[5];
    const float* W2     = (const float*)d_in[6];
    const float* b2     = (const float*)d_in[7];
    const float* Wq     = (const float*)d_in[8];
    const float* bq     = (const float*)d_in[9];
    const float* Wk     = (const float*)d_in[10];
    const float* bk     = (const float*)d_in[11];
    const float* Wv     = (const float*)d_in[12];
    const float* bv     = (const float*)d_in[13];
    const float* Wo     = (const float*)d_in[14];
    const float* bo     = (const float*)d_in[15];
    float* out = (float*)d_out;

    char* ws = (char*)d_ws;
    u16*   Afrag   = (u16*)(ws);              // 32768 B
    u16*   Wovfrag = (u16*)(ws + 32768);      // 32768 B
    u16*   W1frag  = (u16*)(ws + 65536);      // 8192 B
    u16*   W2frag  = (u16*)(ws + 73728);      // 8192 B
    u16*   W2Tfrag = (u16*)(ws + 81920);      // 8192 B
    float* bA      = (float*)(ws + 90112);    // 512 B
    float* su      = (float*)(ws + 90624);    // 512 B
    float* bov     = (float*)(ws + 91136);    // 512 B
    float* d0      = (float*)(ws + 91648);    // 16 B
    u16*   xT      = (u16*)(ws + 94208);      // 4 MiB

    k_pt<<<2178, 512, 0, stream>>>(x, Wq, bq, Wk, bk, Wv, bv, Wo, bo, W1, W2,
                                   Afrag, Wovfrag, W1frag, W2frag, W2Tfrag,
                                   bA, su, bov, d0, xT);
    k_main<<<2048, 256, 0, stream>>>(xT, coords, idx, Bg, b1, b2,
                                     Afrag, Wovfrag, W1frag, W2frag, W2Tfrag,
                                     bA, su, bov, d0, out);
}